// Round 9
// baseline (384.039 us; speedup 1.0000x reference)
//
#include <hip/hip_runtime.h>
#include <hip/hip_bf16.h>
#include <hip/hip_fp16.h>
#include <math.h>

#define NN 512

// smearing constants
#define START 0.006737946999085467f            // exp(-5)
#define STEP  ((1.0f - START) * (1.0f/15.0f))  // linspace step
#define SB    (0.125f * (1.0f - START))
#define BETA  (1.0f/(SB*SB))
#define LOG2E 1.4426950408889634f
#define NB    (-(BETA)*LOG2E)                  // exp(-beta t^2) = exp2(NB t^2)

// ===========================================================================
// R9 == R8 with the __floats2half2_rn(x,y) 2-arg signature fixed.
// Single-barrier blocks + fp16 G + transposed operands.
//  - R7 lesson: VGPR=36 + barriers between load-issue and use => compiler
//    serializes loads (41 us). Here the contract loop has NO barriers.
//  - k0 transposes W to Wt[a][j][c][r]; k1b stores att2 transposed
//    [j][q2][c][r]  => contract loads are 4x float4 per kq (contiguous).
//  - G precomputed once per block for all 64 j into LDS as fp16 (32 B/(i,j)).
//  - Grid 1024 = 128 i-tiles(x4) x 8 j-chunks(x64). 256 thr = 16c x 16js.
// ===========================================================================

__global__ __launch_bounds__(256) void k0(const float* __restrict__ W,
                                          float* __restrict__ Wt)
{
    __shared__ float ldsb[256];
    const int row = blockIdx.x;                // (a,j) 0..1023
    ldsb[threadIdx.x] = W[(size_t)row*256 + threadIdx.x];
    __syncthreads();
    const int c = threadIdx.x >> 4, r = threadIdx.x & 15;
    Wt[(size_t)row*256 + threadIdx.x] = ldsb[r*16 + c];   // Wt[row][c][r]
}

// ---------------------------------------------------------------------------
// k1a: stage-1 partials. part1[i][jc][96], 96 = kq*48 + b*16 + c.
// ---------------------------------------------------------------------------
__global__ __launch_bounds__(256,3) void k1a(const float* __restrict__ x,
                                             const float* __restrict__ Wt,
                                             float* __restrict__ part1)
{
    const int ib = blockIdx.x & 127, jc = blockIdx.x >> 7;
    const int i0 = ib * 4;
    const int tid = threadIdx.x;
    const int c = tid & 15, js = tid >> 4;
    const int lane = tid & 63, wv = tid >> 6;

    __shared__ __half lG[4][64][16];           // 32 B per (i,j)
    __shared__ float4 lP[4][64];
    __shared__ float s_part[4][16][26];

    // ---- phase 1: G + d for all (4 i) x (64 j), one (i,j) per thread ----
    {
        const int pi = tid >> 6, pj = tid & 63;
        const int jg = jc*64 + pj;
        const float xi0 = x[(i0+pi)*3+0], xi1 = x[(i0+pi)*3+1], xi2 = x[(i0+pi)*3+2];
        float d0 = xi0 - x[jg*3+0];
        float d1 = xi1 - x[jg*3+1];
        float d2 = xi2 - x[jg*3+2];
        float nsq = fmaf(d0,d0, fmaf(d1,d1, fmaf(d2,d2, 1e-6f)));
        float rs  = __builtin_amdgcn_rsqf(nsq);
        float nrm = nsq * rs;
        float inv = rs * rs;
        float cutv = 0.f;
        if (nrm < 5.0f) cutv = 0.5f*(__cosf(nrm*0.6283185307179586f)+1.0f);
        float en = exp2f(-LOG2E * nrm);
        lP[pi][pj] = make_float4(d0*inv, d1*inv, d2*inv, 0.f);
        __half2* dst = reinterpret_cast<__half2*>(&lG[pi][pj][0]);
        #pragma unroll
        for (int r2 = 0; r2 < 8; ++r2) {
            float t0 = en - (START + STEP*(float)(2*r2+0));
            float t1 = en - (START + STEP*(float)(2*r2+1));
            dst[r2] = __floats2half2_rn(cutv*exp2f(NB*t0*t0),
                                        cutv*exp2f(NB*t1*t1));
        }
    }
    __syncthreads();                            // the ONLY main-loop barrier

    float acc[24];                              // i*6 + kq*3 + b
    #pragma unroll
    for (int v = 0; v < 24; ++v) acc[v] = 0.f;

    #pragma unroll
    for (int t = 0; t < 4; ++t) {
        const int jl = js + 16*t;
        const int jg = jc*64 + jl;
        const float4* Kp = reinterpret_cast<const float4*>(Wt + (size_t)jg*256 + c*16);
        const float4* Qp = reinterpret_cast<const float4*>(Wt + (size_t)NN*256 + (size_t)jg*256 + c*16);
        float4 ka = Kp[0], kb = Kp[1], kc = Kp[2], kd = Kp[3];
        float4 qa = Qp[0], qb = Qp[1], qc = Qp[2], qd = Qp[3];

        #pragma unroll
        for (int i = 0; i < 4; ++i) {
            const float4* gp = reinterpret_cast<const float4*>(&lG[i][jl][0]);
            float4 g0 = gp[0], g1 = gp[1];
            const __half2* h0 = reinterpret_cast<const __half2*>(&g0);
            const __half2* h1 = reinterpret_cast<const __half2*>(&g1);
            float2 p0 = __half22float2(h0[0]);
            float2 p1 = __half22float2(h0[1]);
            float2 p2 = __half22float2(h0[2]);
            float2 p3 = __half22float2(h0[3]);
            float2 p4 = __half22float2(h1[0]);
            float2 p5 = __half22float2(h1[1]);
            float2 p6 = __half22float2(h1[2]);
            float2 p7 = __half22float2(h1[3]);
            float tk, tq;
            tk = p0.x*ka.x; tq = p0.x*qa.x;
            tk = fmaf(p0.y,ka.y,tk); tq = fmaf(p0.y,qa.y,tq);
            tk = fmaf(p1.x,ka.z,tk); tq = fmaf(p1.x,qa.z,tq);
            tk = fmaf(p1.y,ka.w,tk); tq = fmaf(p1.y,qa.w,tq);
            tk = fmaf(p2.x,kb.x,tk); tq = fmaf(p2.x,qb.x,tq);
            tk = fmaf(p2.y,kb.y,tk); tq = fmaf(p2.y,qb.y,tq);
            tk = fmaf(p3.x,kb.z,tk); tq = fmaf(p3.x,qb.z,tq);
            tk = fmaf(p3.y,kb.w,tk); tq = fmaf(p3.y,qb.w,tq);
            tk = fmaf(p4.x,kc.x,tk); tq = fmaf(p4.x,qc.x,tq);
            tk = fmaf(p4.y,kc.y,tk); tq = fmaf(p4.y,qc.y,tq);
            tk = fmaf(p5.x,kc.z,tk); tq = fmaf(p5.x,qc.z,tq);
            tk = fmaf(p5.y,kc.w,tk); tq = fmaf(p5.y,qc.w,tq);
            tk = fmaf(p6.x,kd.x,tk); tq = fmaf(p6.x,qd.x,tq);
            tk = fmaf(p6.y,kd.y,tk); tq = fmaf(p6.y,qd.y,tq);
            tk = fmaf(p7.x,kd.z,tk); tq = fmaf(p7.x,qd.z,tq);
            tk = fmaf(p7.y,kd.w,tk); tq = fmaf(p7.y,qd.w,tq);
            float4 dd = lP[i][jl];
            acc[i*6+0] = fmaf(tk, dd.x, acc[i*6+0]);
            acc[i*6+1] = fmaf(tk, dd.y, acc[i*6+1]);
            acc[i*6+2] = fmaf(tk, dd.z, acc[i*6+2]);
            acc[i*6+3] = fmaf(tq, dd.x, acc[i*6+3]);
            acc[i*6+4] = fmaf(tq, dd.y, acc[i*6+4]);
            acc[i*6+5] = fmaf(tq, dd.z, acc[i*6+5]);
        }
    }

    #pragma unroll
    for (int v = 0; v < 24; ++v) {
        float t = acc[v];
        t += __shfl_xor(t, 16);
        t += __shfl_xor(t, 32);
        if (lane < 16) s_part[wv][c][v] = t;
    }
    __syncthreads();

    for (int v = tid; v < 384; v += 256) {
        int i = v / 96, o = v - i*96;
        int kq = o / 48, rem = o - kq*48;
        int b = rem >> 4, c2 = rem & 15;
        int f = i*6 + kq*3 + b;
        float sum = s_part[0][c2][f] + s_part[1][c2][f]
                  + s_part[2][c2][f] + s_part[3][c2][f];
        part1[(i0+i)*768 + jc*96 + o] = sum;
    }
}

// ---------------------------------------------------------------------------
// k1b: reduce 8 partials -> att1 -> silu(W1) -> att2 row (TRANSPOSED store).
// att2t[i][q2][c][r] = att2[i][q2*256 + r*16 + c]
// ---------------------------------------------------------------------------
__global__ __launch_bounds__(256) void k1b(const float* __restrict__ part1,
                                           const float* __restrict__ W1,
                                           const float* __restrict__ b1,
                                           const float* __restrict__ W2,
                                           float* __restrict__ att2t)
{
    const int i = blockIdx.x;
    const int tid = threadIdx.x;
    __shared__ float s_bkq[96];
    __shared__ float s_att[256];
    __shared__ float s_z[16][16];
    __shared__ float s_a1[16];

    if (tid < 96) {
        const float* p = part1 + i*768 + tid;
        float s = 0.f;
        #pragma unroll
        for (int k = 0; k < 8; ++k) s += p[k*96];
        s_bkq[tid] = s;
    }
    __syncthreads();

    {
        int h = tid >> 4, g = tid & 15;
        s_att[tid] = s_bkq[     h]*s_bkq[48+     g]
                   + s_bkq[16 + h]*s_bkq[48+16 + g]
                   + s_bkq[32 + h]*s_bkq[48+32 + g];
    }
    __syncthreads();

    {
        int h = tid & 15, seg = tid >> 4;
        const float* w1 = W1 + h*256 + seg*16;
        const float* a  = s_att + seg*16;
        float p = 0.f;
        #pragma unroll
        for (int k = 0; k < 16; ++k) p = fmaf(a[k], w1[k], p);
        s_z[seg][h] = p;
    }
    __syncthreads();

    if (tid < 16) {
        float z = b1[tid];
        #pragma unroll
        for (int seg = 0; seg < 16; ++seg) z += s_z[seg][tid];
        s_a1[tid] = z / (1.0f + __expf(-z));
    }
    __syncthreads();

    float a1[16];
    #pragma unroll
    for (int cc = 0; cc < 16; ++cc) a1[cc] = s_a1[cc];
    #pragma unroll
    for (int p = 0; p < 4; ++p) {
        int o = tid + p*256;
        const float4* w2 = reinterpret_cast<const float4*>(W2 + o*16);
        float4 wa = w2[0], wb = w2[1], wc = w2[2], wd = w2[3];
        float accv = wa.x*a1[0] + wa.y*a1[1] + wa.z*a1[2] + wa.w*a1[3]
                   + wb.x*a1[4] + wb.y*a1[5] + wb.z*a1[6] + wb.w*a1[7]
                   + wc.x*a1[8] + wc.y*a1[9] + wc.z*a1[10]+ wc.w*a1[11]
                   + wd.x*a1[12]+ wd.y*a1[13]+ wd.z*a1[14]+ wd.w*a1[15];
        // transposed store: q2 = o>>8, r = (o>>4)&15, c = o&15
        att2t[i*1024 + ((o>>8)*256) + ((o&15)*16) + ((o>>4)&15)] = accv;
    }
}

// ---------------------------------------------------------------------------
// k2a: stage-3 right-term + S partials. part2[i][jc][144].
// ---------------------------------------------------------------------------
__global__ __launch_bounds__(256,3) void k2a(const float* __restrict__ x,
                                             const float* __restrict__ att2t,
                                             float* __restrict__ part2)
{
    const int ib = blockIdx.x & 127, jc = blockIdx.x >> 7;
    const int i0 = ib * 4;
    const int tid = threadIdx.x;
    const int c = tid & 15, js = tid >> 4;
    const int lane = tid & 63, wv = tid >> 6;

    __shared__ __half lG[4][64][16];
    __shared__ float4 lP[4][64];
    __shared__ float s_part[4][16][38];

    {
        const int pi = tid >> 6, pj = tid & 63;
        const int jg = jc*64 + pj;
        const float xi0 = x[(i0+pi)*3+0], xi1 = x[(i0+pi)*3+1], xi2 = x[(i0+pi)*3+2];
        float d0 = xi0 - x[jg*3+0];
        float d1 = xi1 - x[jg*3+1];
        float d2 = xi2 - x[jg*3+2];
        float nsq = fmaf(d0,d0, fmaf(d1,d1, fmaf(d2,d2, 1e-6f)));
        float rs  = __builtin_amdgcn_rsqf(nsq);
        float nrm = nsq * rs;
        float inv = rs * rs;
        float cutv = 0.f;
        if (nrm < 5.0f) cutv = 0.5f*(__cosf(nrm*0.6283185307179586f)+1.0f);
        float en = exp2f(-LOG2E * nrm);
        lP[pi][pj] = make_float4(d0*inv, d1*inv, d2*inv, 0.f);
        __half2* dst = reinterpret_cast<__half2*>(&lG[pi][pj][0]);
        #pragma unroll
        for (int r2 = 0; r2 < 8; ++r2) {
            float t0 = en - (START + STEP*(float)(2*r2+0));
            float t1 = en - (START + STEP*(float)(2*r2+1));
            dst[r2] = __floats2half2_rn(cutv*exp2f(NB*t0*t0),
                                        cutv*exp2f(NB*t1*t1));
        }
    }
    __syncthreads();

    float acc[36];                              // 24 main + 12 S (24+i*3+b, r=c)
    #pragma unroll
    for (int v = 0; v < 36; ++v) acc[v] = 0.f;

    #pragma unroll
    for (int t = 0; t < 4; ++t) {
        const int jl = js + 16*t;
        const int jg = jc*64 + jl;
        const float4* Kp = reinterpret_cast<const float4*>(att2t + (size_t)jg*1024 + 512 + c*16);
        const float4* Qp = reinterpret_cast<const float4*>(att2t + (size_t)jg*1024 + 768 + c*16);
        float4 ka = Kp[0], kb = Kp[1], kc = Kp[2], kd = Kp[3];
        float4 qa = Qp[0], qb = Qp[1], qc = Qp[2], qd = Qp[3];

        #pragma unroll
        for (int i = 0; i < 4; ++i) {
            const float4* gp = reinterpret_cast<const float4*>(&lG[i][jl][0]);
            float4 g0 = gp[0], g1 = gp[1];
            const __half2* h0 = reinterpret_cast<const __half2*>(&g0);
            const __half2* h1 = reinterpret_cast<const __half2*>(&g1);
            float2 p0 = __half22float2(h0[0]);
            float2 p1 = __half22float2(h0[1]);
            float2 p2 = __half22float2(h0[2]);
            float2 p3 = __half22float2(h0[3]);
            float2 p4 = __half22float2(h1[0]);
            float2 p5 = __half22float2(h1[1]);
            float2 p6 = __half22float2(h1[2]);
            float2 p7 = __half22float2(h1[3]);
            float tk, tq;
            tk = p0.x*ka.x; tq = p0.x*qa.x;
            tk = fmaf(p0.y,ka.y,tk); tq = fmaf(p0.y,qa.y,tq);
            tk = fmaf(p1.x,ka.z,tk); tq = fmaf(p1.x,qa.z,tq);
            tk = fmaf(p1.y,ka.w,tk); tq = fmaf(p1.y,qa.w,tq);
            tk = fmaf(p2.x,kb.x,tk); tq = fmaf(p2.x,qb.x,tq);
            tk = fmaf(p2.y,kb.y,tk); tq = fmaf(p2.y,qb.y,tq);
            tk = fmaf(p3.x,kb.z,tk); tq = fmaf(p3.x,qb.z,tq);
            tk = fmaf(p3.y,kb.w,tk); tq = fmaf(p3.y,qb.w,tq);
            tk = fmaf(p4.x,kc.x,tk); tq = fmaf(p4.x,qc.x,tq);
            tk = fmaf(p4.y,kc.y,tk); tq = fmaf(p4.y,qc.y,tq);
            tk = fmaf(p5.x,kc.z,tk); tq = fmaf(p5.x,qc.z,tq);
            tk = fmaf(p5.y,kc.w,tk); tq = fmaf(p5.y,qc.w,tq);
            tk = fmaf(p6.x,kd.x,tk); tq = fmaf(p6.x,qd.x,tq);
            tk = fmaf(p6.y,kd.y,tk); tq = fmaf(p6.y,qd.y,tq);
            tk = fmaf(p7.x,kd.z,tk); tq = fmaf(p7.x,qd.z,tq);
            tk = fmaf(p7.y,kd.w,tk); tq = fmaf(p7.y,qd.w,tq);
            float4 dd = lP[i][jl];
            acc[i*6+0] = fmaf(tk, dd.x, acc[i*6+0]);
            acc[i*6+1] = fmaf(tk, dd.y, acc[i*6+1]);
            acc[i*6+2] = fmaf(tk, dd.z, acc[i*6+2]);
            acc[i*6+3] = fmaf(tq, dd.x, acc[i*6+3]);
            acc[i*6+4] = fmaf(tq, dd.y, acc[i*6+4]);
            acc[i*6+5] = fmaf(tq, dd.z, acc[i*6+5]);
            // S: this lane owns r=c
            __half2 hcv = *reinterpret_cast<const __half2*>(&lG[i][jl][c & 14]);
            float2 fc = __half22float2(hcv);
            float gc = (c & 1) ? fc.y : fc.x;
            acc[24+i*3+0] = fmaf(gc, dd.x, acc[24+i*3+0]);
            acc[24+i*3+1] = fmaf(gc, dd.y, acc[24+i*3+1]);
            acc[24+i*3+2] = fmaf(gc, dd.z, acc[24+i*3+2]);
        }
    }

    #pragma unroll
    for (int v = 0; v < 36; ++v) {
        float t = acc[v];
        t += __shfl_xor(t, 16);
        t += __shfl_xor(t, 32);
        if (lane < 16) s_part[wv][c][v] = t;
    }
    __syncthreads();

    for (int v = tid; v < 576; v += 256) {
        int i = v / 144, o = v - i*144;
        int c2, f;
        if (o < 96) {
            int kq = o / 48, rem = o - kq*48;
            int b = rem >> 4; c2 = rem & 15;
            f = i*6 + kq*3 + b;
        } else {
            int oS = o - 96;
            int r = oS / 3, b = oS - r*3;
            c2 = r;
            f = 24 + i*3 + b;
        }
        float sum = s_part[0][c2][f] + s_part[1][c2][f]
                  + s_part[2][c2][f] + s_part[3][c2][f];
        part2[(i0+i)*1152 + jc*144 + o] = sum;
    }
}

// ---------------------------------------------------------------------------
// k2b: reduce 8 partials + left-term (transposed att2t rows) -> out. Grid 512.
// ---------------------------------------------------------------------------
__global__ __launch_bounds__(256) void k2b(const float* __restrict__ att2t,
                                           const float* __restrict__ part2,
                                           const float* __restrict__ W3,
                                           const float* __restrict__ b3,
                                           const float* __restrict__ W4,
                                           const float* __restrict__ b4,
                                           float* __restrict__ out)
{
    const int i = blockIdx.x;
    const int tid = threadIdx.x;
    __shared__ float s_red[144];
    __shared__ float s_att[256];
    __shared__ float s_z[16][16];
    __shared__ float s_a1[16];

    if (tid < 144) {
        const float* p = part2 + i*1152 + tid;
        float s = 0.f;
        #pragma unroll
        for (int k = 0; k < 8; ++k) s += p[k*144];
        s_red[tid] = s;
    }
    __syncthreads();

    if (tid < 96) {                      // left-term: bkq[c,b] += sum_r left[r,c]*S[r,b]
        int kq = tid / 48, rem = tid - kq*48;
        int b = rem >> 4, cc = rem & 15;
        const float4* lrow = reinterpret_cast<const float4*>(att2t + i*1024 + kq*256 + cc*16);
        float4 A = lrow[0], B = lrow[1], C = lrow[2], D = lrow[3];
        float add = 0.f;
        add = fmaf(A.x, s_red[96+ 0*3+b], add);
        add = fmaf(A.y, s_red[96+ 1*3+b], add);
        add = fmaf(A.z, s_red[96+ 2*3+b], add);
        add = fmaf(A.w, s_red[96+ 3*3+b], add);
        add = fmaf(B.x, s_red[96+ 4*3+b], add);
        add = fmaf(B.y, s_red[96+ 5*3+b], add);
        add = fmaf(B.z, s_red[96+ 6*3+b], add);
        add = fmaf(B.w, s_red[96+ 7*3+b], add);
        add = fmaf(C.x, s_red[96+ 8*3+b], add);
        add = fmaf(C.y, s_red[96+ 9*3+b], add);
        add = fmaf(C.z, s_red[96+10*3+b], add);
        add = fmaf(C.w, s_red[96+11*3+b], add);
        add = fmaf(D.x, s_red[96+12*3+b], add);
        add = fmaf(D.y, s_red[96+13*3+b], add);
        add = fmaf(D.z, s_red[96+14*3+b], add);
        add = fmaf(D.w, s_red[96+15*3+b], add);
        s_red[tid] += add;
    }
    __syncthreads();

    {
        int h = tid >> 4, g = tid & 15;
        s_att[tid] = s_red[     h]*s_red[48+     g]
                   + s_red[16 + h]*s_red[48+16 + g]
                   + s_red[32 + h]*s_red[48+32 + g];
    }
    __syncthreads();

    {
        int h = tid & 15, seg = tid >> 4;
        const float* w3 = W3 + h*256 + seg*16;
        const float* a  = s_att + seg*16;
        float p = 0.f;
        #pragma unroll
        for (int k = 0; k < 16; ++k) p = fmaf(a[k], w3[k], p);
        s_z[seg][h] = p;
    }
    __syncthreads();

    if (tid < 16) {
        float z = b3[tid];
        #pragma unroll
        for (int seg = 0; seg < 16; ++seg) z += s_z[seg][tid];
        s_a1[tid] = z / (1.0f + __expf(-z));
    }
    __syncthreads();

    if (tid == 0) {
        float accv = b4[0];
        #pragma unroll
        for (int cc = 0; cc < 16; ++cc) accv = fmaf(s_a1[cc], W4[cc], accv);
        out[i] = accv;
    }
}

extern "C" void kernel_launch(void* const* d_in, const int* in_sizes, int n_in,
                              void* d_out, int out_size, void* d_ws, size_t ws_size,
                              hipStream_t stream) {
    (void)in_sizes; (void)n_in; (void)out_size; (void)ws_size;
    const float* x  = (const float*)d_in[0];
    const float* W  = (const float*)d_in[1];
    const float* W1 = (const float*)d_in[2];
    const float* b1 = (const float*)d_in[3];
    const float* W2 = (const float*)d_in[4];
    const float* W3 = (const float*)d_in[5];
    const float* b3 = (const float*)d_in[6];
    const float* W4 = (const float*)d_in[7];
    const float* b4 = (const float*)d_in[8];

    float* att2t = (float*)d_ws;             // 512*1024
    float* part1 = att2t + 512*1024;         // 512*768
    float* part2 = part1 + 512*768;          // 512*1152
    float* Wt    = part2 + 512*1152;         // 2*512*256
    float* out   = (float*)d_out;

    k0 <<<1024, 256, 0, stream>>>(W, Wt);
    k1a<<<1024, 256, 0, stream>>>(x, Wt, part1);
    k1b<<< 512, 256, 0, stream>>>(part1, W1, b1, W2, att2t);
    k2a<<<1024, 256, 0, stream>>>(x, att2t, part2);
    k2b<<< 512, 256, 0, stream>>>(att2t, part2, W3, b3, W4, b4, out);
}

// Round 10
// 119.346 us; speedup vs baseline: 3.2179x; 3.2179x over previous
//
#include <hip/hip_runtime.h>
#include <hip/hip_bf16.h>
#include <math.h>

#define NN 512

// smearing constants
#define START 0.006737946999085467f            // exp(-5)
#define STEP  ((1.0f - START) * (1.0f/15.0f))  // linspace step
#define SB    (0.125f * (1.0f - START))
#define BETA  (1.0f/(SB*SB))
#define LOG2E 1.4426950408889634f
#define NB    (-(BETA)*LOG2E)                  // exp(-beta t^2) = exp2(NB t^2)

// ===========================================================================
// R10 = R9 minus the three spill-makers:
//  - NO __launch_bounds__ second arg (R9's ",3" clamped VGPR to 84 -> 210 MB
//    scratch spill). Let the allocator size itself.
//  - t-loop NOT unrolled (#pragma unroll 1): only ONE tile's 8 float4 staged
//    loads in flight, live set ~110 regs.
//  - G back to fp32 LDS (R6-proven; no cvt; absmax back to ~4e-3).
// Kept from R9: k0 W-transpose + transposed att2t (float4 contract loads).
// Grid 1024 = 128 i-tiles(x4) x 8 j-chunks(x64). 256 thr = 16c x 16js.
// ===========================================================================

__global__ __launch_bounds__(256) void k0(const float* __restrict__ W,
                                          float* __restrict__ Wt)
{
    __shared__ float ldsb[256];
    const int row = blockIdx.x;                // (a,j) 0..1023
    ldsb[threadIdx.x] = W[(size_t)row*256 + threadIdx.x];
    __syncthreads();
    const int c = threadIdx.x >> 4, r = threadIdx.x & 15;
    Wt[(size_t)row*256 + threadIdx.x] = ldsb[r*16 + c];   // Wt[row][c][r]
}

// ---------------------------------------------------------------------------
// k1a: stage-1 partials. part1[i][jc][96], 96 = kq*48 + b*16 + c.
// ---------------------------------------------------------------------------
__global__ __launch_bounds__(256) void k1a(const float* __restrict__ x,
                                           const float* __restrict__ Wt,
                                           float* __restrict__ part1)
{
    const int ib = blockIdx.x & 127, jc = blockIdx.x >> 7;
    const int i0 = ib * 4;
    const int tid = threadIdx.x;
    const int c = tid & 15, js = tid >> 4;
    const int lane = tid & 63, wv = tid >> 6;

    __shared__ float  lG[4][64][16];           // fp32 G
    __shared__ float4 lP[4][64];
    __shared__ float  s_part[4][16][26];

    // ---- phase 1: G + d for all (4 i) x (64 j), one (i,j) per thread ----
    {
        const int pi = tid >> 6, pj = tid & 63;
        const int jg = jc*64 + pj;
        const float xi0 = x[(i0+pi)*3+0], xi1 = x[(i0+pi)*3+1], xi2 = x[(i0+pi)*3+2];
        float d0 = xi0 - x[jg*3+0];
        float d1 = xi1 - x[jg*3+1];
        float d2 = xi2 - x[jg*3+2];
        float nsq = fmaf(d0,d0, fmaf(d1,d1, fmaf(d2,d2, 1e-6f)));
        float rs  = __builtin_amdgcn_rsqf(nsq);
        float nrm = nsq * rs;
        float inv = rs * rs;
        float cutv = 0.f;
        if (nrm < 5.0f) cutv = 0.5f*(__cosf(nrm*0.6283185307179586f)+1.0f);
        float en = exp2f(-LOG2E * nrm);
        lP[pi][pj] = make_float4(d0*inv, d1*inv, d2*inv, 0.f);
        float4* dst = reinterpret_cast<float4*>(&lG[pi][pj][0]);
        #pragma unroll
        for (int rq = 0; rq < 4; ++rq) {
            float t0 = en - (START + STEP*(float)(4*rq+0));
            float t1 = en - (START + STEP*(float)(4*rq+1));
            float t2 = en - (START + STEP*(float)(4*rq+2));
            float t3 = en - (START + STEP*(float)(4*rq+3));
            dst[rq] = make_float4(cutv*exp2f(NB*t0*t0), cutv*exp2f(NB*t1*t1),
                                  cutv*exp2f(NB*t2*t2), cutv*exp2f(NB*t3*t3));
        }
    }
    __syncthreads();                            // the ONLY main-loop barrier

    float acc[24];                              // i*6 + kq*3 + b
    #pragma unroll
    for (int v = 0; v < 24; ++v) acc[v] = 0.f;

    #pragma unroll 1
    for (int t = 0; t < 4; ++t) {
        const int jl = js + 16*t;
        const int jg = jc*64 + jl;
        const float4* Kp = reinterpret_cast<const float4*>(Wt + (size_t)jg*256 + c*16);
        const float4* Qp = reinterpret_cast<const float4*>(Wt + (size_t)NN*256 + (size_t)jg*256 + c*16);
        float4 ka = Kp[0], kb = Kp[1], kc = Kp[2], kd = Kp[3];
        float4 qa = Qp[0], qb = Qp[1], qc = Qp[2], qd = Qp[3];

        #pragma unroll
        for (int i = 0; i < 4; ++i) {
            const float4* gp = reinterpret_cast<const float4*>(&lG[i][jl][0]);
            float4 g0 = gp[0], g1 = gp[1], g2 = gp[2], g3 = gp[3];
            float tk, tq;
            tk = g0.x*ka.x; tq = g0.x*qa.x;
            tk = fmaf(g0.y,ka.y,tk); tq = fmaf(g0.y,qa.y,tq);
            tk = fmaf(g0.z,ka.z,tk); tq = fmaf(g0.z,qa.z,tq);
            tk = fmaf(g0.w,ka.w,tk); tq = fmaf(g0.w,qa.w,tq);
            tk = fmaf(g1.x,kb.x,tk); tq = fmaf(g1.x,qb.x,tq);
            tk = fmaf(g1.y,kb.y,tk); tq = fmaf(g1.y,qb.y,tq);
            tk = fmaf(g1.z,kb.z,tk); tq = fmaf(g1.z,qb.z,tq);
            tk = fmaf(g1.w,kb.w,tk); tq = fmaf(g1.w,qb.w,tq);
            tk = fmaf(g2.x,kc.x,tk); tq = fmaf(g2.x,qc.x,tq);
            tk = fmaf(g2.y,kc.y,tk); tq = fmaf(g2.y,qc.y,tq);
            tk = fmaf(g2.z,kc.z,tk); tq = fmaf(g2.z,qc.z,tq);
            tk = fmaf(g2.w,kc.w,tk); tq = fmaf(g2.w,qc.w,tq);
            tk = fmaf(g3.x,kd.x,tk); tq = fmaf(g3.x,qd.x,tq);
            tk = fmaf(g3.y,kd.y,tk); tq = fmaf(g3.y,qd.y,tq);
            tk = fmaf(g3.z,kd.z,tk); tq = fmaf(g3.z,qd.z,tq);
            tk = fmaf(g3.w,kd.w,tk); tq = fmaf(g3.w,qd.w,tq);
            float4 dd = lP[i][jl];
            acc[i*6+0] = fmaf(tk, dd.x, acc[i*6+0]);
            acc[i*6+1] = fmaf(tk, dd.y, acc[i*6+1]);
            acc[i*6+2] = fmaf(tk, dd.z, acc[i*6+2]);
            acc[i*6+3] = fmaf(tq, dd.x, acc[i*6+3]);
            acc[i*6+4] = fmaf(tq, dd.y, acc[i*6+4]);
            acc[i*6+5] = fmaf(tq, dd.z, acc[i*6+5]);
        }
    }

    #pragma unroll
    for (int v = 0; v < 24; ++v) {
        float t = acc[v];
        t += __shfl_xor(t, 16);
        t += __shfl_xor(t, 32);
        if (lane < 16) s_part[wv][c][v] = t;
    }
    __syncthreads();

    for (int v = tid; v < 384; v += 256) {
        int i = v / 96, o = v - i*96;
        int kq = o / 48, rem = o - kq*48;
        int b = rem >> 4, c2 = rem & 15;
        int f = i*6 + kq*3 + b;
        float sum = s_part[0][c2][f] + s_part[1][c2][f]
                  + s_part[2][c2][f] + s_part[3][c2][f];
        part1[(i0+i)*768 + jc*96 + o] = sum;
    }
}

// ---------------------------------------------------------------------------
// k1b: reduce 8 partials -> att1 -> silu(W1) -> att2 row (TRANSPOSED store).
// att2t[i][q2][c][r] = att2[i][q2*256 + r*16 + c]
// ---------------------------------------------------------------------------
__global__ __launch_bounds__(256) void k1b(const float* __restrict__ part1,
                                           const float* __restrict__ W1,
                                           const float* __restrict__ b1,
                                           const float* __restrict__ W2,
                                           float* __restrict__ att2t)
{
    const int i = blockIdx.x;
    const int tid = threadIdx.x;
    __shared__ float s_bkq[96];
    __shared__ float s_att[256];
    __shared__ float s_z[16][16];
    __shared__ float s_a1[16];

    if (tid < 96) {
        const float* p = part1 + i*768 + tid;
        float s = 0.f;
        #pragma unroll
        for (int k = 0; k < 8; ++k) s += p[k*96];
        s_bkq[tid] = s;
    }
    __syncthreads();

    {
        int h = tid >> 4, g = tid & 15;
        s_att[tid] = s_bkq[     h]*s_bkq[48+     g]
                   + s_bkq[16 + h]*s_bkq[48+16 + g]
                   + s_bkq[32 + h]*s_bkq[48+32 + g];
    }
    __syncthreads();

    {
        int h = tid & 15, seg = tid >> 4;
        const float* w1 = W1 + h*256 + seg*16;
        const float* a  = s_att + seg*16;
        float p = 0.f;
        #pragma unroll
        for (int k = 0; k < 16; ++k) p = fmaf(a[k], w1[k], p);
        s_z[seg][h] = p;
    }
    __syncthreads();

    if (tid < 16) {
        float z = b1[tid];
        #pragma unroll
        for (int seg = 0; seg < 16; ++seg) z += s_z[seg][tid];
        s_a1[tid] = z / (1.0f + __expf(-z));
    }
    __syncthreads();

    float a1[16];
    #pragma unroll
    for (int cc = 0; cc < 16; ++cc) a1[cc] = s_a1[cc];
    #pragma unroll
    for (int p = 0; p < 4; ++p) {
        int o = tid + p*256;
        const float4* w2 = reinterpret_cast<const float4*>(W2 + o*16);
        float4 wa = w2[0], wb = w2[1], wc = w2[2], wd = w2[3];
        float accv = wa.x*a1[0] + wa.y*a1[1] + wa.z*a1[2] + wa.w*a1[3]
                   + wb.x*a1[4] + wb.y*a1[5] + wb.z*a1[6] + wb.w*a1[7]
                   + wc.x*a1[8] + wc.y*a1[9] + wc.z*a1[10]+ wc.w*a1[11]
                   + wd.x*a1[12]+ wd.y*a1[13]+ wd.z*a1[14]+ wd.w*a1[15];
        // transposed store: q2 = o>>8, r = (o>>4)&15, c = o&15
        att2t[i*1024 + ((o>>8)*256) + ((o&15)*16) + ((o>>4)&15)] = accv;
    }
}

// ---------------------------------------------------------------------------
// k2a: stage-3 right-term + S partials. part2[i][jc][144].
// ---------------------------------------------------------------------------
__global__ __launch_bounds__(256) void k2a(const float* __restrict__ x,
                                           const float* __restrict__ att2t,
                                           float* __restrict__ part2)
{
    const int ib = blockIdx.x & 127, jc = blockIdx.x >> 7;
    const int i0 = ib * 4;
    const int tid = threadIdx.x;
    const int c = tid & 15, js = tid >> 4;
    const int lane = tid & 63, wv = tid >> 6;

    __shared__ float  lG[4][64][16];
    __shared__ float4 lP[4][64];
    __shared__ float  s_part[4][16][38];

    {
        const int pi = tid >> 6, pj = tid & 63;
        const int jg = jc*64 + pj;
        const float xi0 = x[(i0+pi)*3+0], xi1 = x[(i0+pi)*3+1], xi2 = x[(i0+pi)*3+2];
        float d0 = xi0 - x[jg*3+0];
        float d1 = xi1 - x[jg*3+1];
        float d2 = xi2 - x[jg*3+2];
        float nsq = fmaf(d0,d0, fmaf(d1,d1, fmaf(d2,d2, 1e-6f)));
        float rs  = __builtin_amdgcn_rsqf(nsq);
        float nrm = nsq * rs;
        float inv = rs * rs;
        float cutv = 0.f;
        if (nrm < 5.0f) cutv = 0.5f*(__cosf(nrm*0.6283185307179586f)+1.0f);
        float en = exp2f(-LOG2E * nrm);
        lP[pi][pj] = make_float4(d0*inv, d1*inv, d2*inv, 0.f);
        float4* dst = reinterpret_cast<float4*>(&lG[pi][pj][0]);
        #pragma unroll
        for (int rq = 0; rq < 4; ++rq) {
            float t0 = en - (START + STEP*(float)(4*rq+0));
            float t1 = en - (START + STEP*(float)(4*rq+1));
            float t2 = en - (START + STEP*(float)(4*rq+2));
            float t3 = en - (START + STEP*(float)(4*rq+3));
            dst[rq] = make_float4(cutv*exp2f(NB*t0*t0), cutv*exp2f(NB*t1*t1),
                                  cutv*exp2f(NB*t2*t2), cutv*exp2f(NB*t3*t3));
        }
    }
    __syncthreads();

    float acc[36];                              // 24 main + 12 S (24+i*3+b, r=c)
    #pragma unroll
    for (int v = 0; v < 36; ++v) acc[v] = 0.f;

    #pragma unroll 1
    for (int t = 0; t < 4; ++t) {
        const int jl = js + 16*t;
        const int jg = jc*64 + jl;
        const float4* Kp = reinterpret_cast<const float4*>(att2t + (size_t)jg*1024 + 512 + c*16);
        const float4* Qp = reinterpret_cast<const float4*>(att2t + (size_t)jg*1024 + 768 + c*16);
        float4 ka = Kp[0], kb = Kp[1], kc = Kp[2], kd = Kp[3];
        float4 qa = Qp[0], qb = Qp[1], qc = Qp[2], qd = Qp[3];

        #pragma unroll
        for (int i = 0; i < 4; ++i) {
            const float4* gp = reinterpret_cast<const float4*>(&lG[i][jl][0]);
            float4 g0 = gp[0], g1 = gp[1], g2 = gp[2], g3 = gp[3];
            float tk, tq;
            tk = g0.x*ka.x; tq = g0.x*qa.x;
            tk = fmaf(g0.y,ka.y,tk); tq = fmaf(g0.y,qa.y,tq);
            tk = fmaf(g0.z,ka.z,tk); tq = fmaf(g0.z,qa.z,tq);
            tk = fmaf(g0.w,ka.w,tk); tq = fmaf(g0.w,qa.w,tq);
            tk = fmaf(g1.x,kb.x,tk); tq = fmaf(g1.x,qb.x,tq);
            tk = fmaf(g1.y,kb.y,tk); tq = fmaf(g1.y,qb.y,tq);
            tk = fmaf(g1.z,kb.z,tk); tq = fmaf(g1.z,qb.z,tq);
            tk = fmaf(g1.w,kb.w,tk); tq = fmaf(g1.w,qb.w,tq);
            tk = fmaf(g2.x,kc.x,tk); tq = fmaf(g2.x,qc.x,tq);
            tk = fmaf(g2.y,kc.y,tk); tq = fmaf(g2.y,qc.y,tq);
            tk = fmaf(g2.z,kc.z,tk); tq = fmaf(g2.z,qc.z,tq);
            tk = fmaf(g2.w,kc.w,tk); tq = fmaf(g2.w,qc.w,tq);
            tk = fmaf(g3.x,kd.x,tk); tq = fmaf(g3.x,qd.x,tq);
            tk = fmaf(g3.y,kd.y,tk); tq = fmaf(g3.y,qd.y,tq);
            tk = fmaf(g3.z,kd.z,tk); tq = fmaf(g3.z,qd.z,tq);
            tk = fmaf(g3.w,kd.w,tk); tq = fmaf(g3.w,qd.w,tq);
            float4 dd = lP[i][jl];
            acc[i*6+0] = fmaf(tk, dd.x, acc[i*6+0]);
            acc[i*6+1] = fmaf(tk, dd.y, acc[i*6+1]);
            acc[i*6+2] = fmaf(tk, dd.z, acc[i*6+2]);
            acc[i*6+3] = fmaf(tq, dd.x, acc[i*6+3]);
            acc[i*6+4] = fmaf(tq, dd.y, acc[i*6+4]);
            acc[i*6+5] = fmaf(tq, dd.z, acc[i*6+5]);
            float gc = lG[i][jl][c];            // this lane's r=c for S
            acc[24+i*3+0] = fmaf(gc, dd.x, acc[24+i*3+0]);
            acc[24+i*3+1] = fmaf(gc, dd.y, acc[24+i*3+1]);
            acc[24+i*3+2] = fmaf(gc, dd.z, acc[24+i*3+2]);
        }
    }

    #pragma unroll
    for (int v = 0; v < 36; ++v) {
        float t = acc[v];
        t += __shfl_xor(t, 16);
        t += __shfl_xor(t, 32);
        if (lane < 16) s_part[wv][c][v] = t;
    }
    __syncthreads();

    for (int v = tid; v < 576; v += 256) {
        int i = v / 144, o = v - i*144;
        int c2, f;
        if (o < 96) {
            int kq = o / 48, rem = o - kq*48;
            int b = rem >> 4; c2 = rem & 15;
            f = i*6 + kq*3 + b;
        } else {
            int oS = o - 96;
            int r = oS / 3, b = oS - r*3;
            c2 = r;
            f = 24 + i*3 + b;
        }
        float sum = s_part[0][c2][f] + s_part[1][c2][f]
                  + s_part[2][c2][f] + s_part[3][c2][f];
        part2[(i0+i)*1152 + jc*144 + o] = sum;
    }
}

// ---------------------------------------------------------------------------
// k2b: reduce 8 partials + left-term (transposed att2t rows) -> out. Grid 512.
// ---------------------------------------------------------------------------
__global__ __launch_bounds__(256) void k2b(const float* __restrict__ att2t,
                                           const float* __restrict__ part2,
                                           const float* __restrict__ W3,
                                           const float* __restrict__ b3,
                                           const float* __restrict__ W4,
                                           const float* __restrict__ b4,
                                           float* __restrict__ out)
{
    const int i = blockIdx.x;
    const int tid = threadIdx.x;
    __shared__ float s_red[144];
    __shared__ float s_att[256];
    __shared__ float s_z[16][16];
    __shared__ float s_a1[16];

    if (tid < 144) {
        const float* p = part2 + i*1152 + tid;
        float s = 0.f;
        #pragma unroll
        for (int k = 0; k < 8; ++k) s += p[k*144];
        s_red[tid] = s;
    }
    __syncthreads();

    if (tid < 96) {                      // left-term: bkq[c,b] += sum_r left[r,c]*S[r,b]
        int kq = tid / 48, rem = tid - kq*48;
        int b = rem >> 4, cc = rem & 15;
        const float4* lrow = reinterpret_cast<const float4*>(att2t + i*1024 + kq*256 + cc*16);
        float4 A = lrow[0], B = lrow[1], C = lrow[2], D = lrow[3];
        float add = 0.f;
        add = fmaf(A.x, s_red[96+ 0*3+b], add);
        add = fmaf(A.y, s_red[96+ 1*3+b], add);
        add = fmaf(A.z, s_red[96+ 2*3+b], add);
        add = fmaf(A.w, s_red[96+ 3*3+b], add);
        add = fmaf(B.x, s_red[96+ 4*3+b], add);
        add = fmaf(B.y, s_red[96+ 5*3+b], add);
        add = fmaf(B.z, s_red[96+ 6*3+b], add);
        add = fmaf(B.w, s_red[96+ 7*3+b], add);
        add = fmaf(C.x, s_red[96+ 8*3+b], add);
        add = fmaf(C.y, s_red[96+ 9*3+b], add);
        add = fmaf(C.z, s_red[96+10*3+b], add);
        add = fmaf(C.w, s_red[96+11*3+b], add);
        add = fmaf(D.x, s_red[96+12*3+b], add);
        add = fmaf(D.y, s_red[96+13*3+b], add);
        add = fmaf(D.z, s_red[96+14*3+b], add);
        add = fmaf(D.w, s_red[96+15*3+b], add);
        s_red[tid] += add;
    }
    __syncthreads();

    {
        int h = tid >> 4, g = tid & 15;
        s_att[tid] = s_red[     h]*s_red[48+     g]
                   + s_red[16 + h]*s_red[48+16 + g]
                   + s_red[32 + h]*s_red[48+32 + g];
    }
    __syncthreads();

    {
        int h = tid & 15, seg = tid >> 4;
        const float* w3 = W3 + h*256 + seg*16;
        const float* a  = s_att + seg*16;
        float p = 0.f;
        #pragma unroll
        for (int k = 0; k < 16; ++k) p = fmaf(a[k], w3[k], p);
        s_z[seg][h] = p;
    }
    __syncthreads();

    if (tid < 16) {
        float z = b3[tid];
        #pragma unroll
        for (int seg = 0; seg < 16; ++seg) z += s_z[seg][tid];
        s_a1[tid] = z / (1.0f + __expf(-z));
    }
    __syncthreads();

    if (tid == 0) {
        float accv = b4[0];
        #pragma unroll
        for (int cc = 0; cc < 16; ++cc) accv = fmaf(s_a1[cc], W4[cc], accv);
        out[i] = accv;
    }
}

extern "C" void kernel_launch(void* const* d_in, const int* in_sizes, int n_in,
                              void* d_out, int out_size, void* d_ws, size_t ws_size,
                              hipStream_t stream) {
    (void)in_sizes; (void)n_in; (void)out_size; (void)ws_size;
    const float* x  = (const float*)d_in[0];
    const float* W  = (const float*)d_in[1];
    const float* W1 = (const float*)d_in[2];
    const float* b1 = (const float*)d_in[3];
    const float* W2 = (const float*)d_in[4];
    const float* W3 = (const float*)d_in[5];
    const float* b3 = (const float*)d_in[6];
    const float* W4 = (const float*)d_in[7];
    const float* b4 = (const float*)d_in[8];

    float* att2t = (float*)d_ws;             // 512*1024
    float* part1 = att2t + 512*1024;         // 512*768
    float* part2 = part1 + 512*768;          // 512*1152
    float* Wt    = part2 + 512*1152;         // 2*512*256
    float* out   = (float*)d_out;

    k0 <<<1024, 256, 0, stream>>>(W, Wt);
    k1a<<<1024, 256, 0, stream>>>(x, Wt, part1);
    k1b<<< 512, 256, 0, stream>>>(part1, W1, b1, W2, att2t);
    k2a<<<1024, 256, 0, stream>>>(x, att2t, part2);
    k2b<<< 512, 256, 0, stream>>>(att2t, part2, W3, b3, W4, b4, out);
}